// Round 7
// baseline (15223.586 us; speedup 1.0000x reference)
//
#include <hip/hip_runtime.h>
#include <stdint.h>

#define BB 32
#define TT 64
#define ID 300
#define HH 168
#define SS 512
#define VV 50257
#define G4 672     // 4*H
#define IC 468     // I + C
#define KP 192     // K padded (8 regions x 24)
#define NP2 50432  // V padded to 128*394
#define NJ 8       // blocks per batch
#define RPB 21     // h rows per block
#define CPB 84     // gate cols per block
#define KK 336     // gate K dim
#define WKP 88     // WgT col pad
#define EPAD 170   // ETs LDS row pad
#define SBLK 64    // s positions per block
#define LSLOT 192  // u64 slots per (b,j) bucket
#define HROW 96    // u32 per hall row (KP/2)
#define NTN 394    // decode n-tiles (50432/128)
#define NTILES 6304 // 16 m-tiles * 394

typedef float f32x4 __attribute__((ext_vector_type(4)));
typedef short bf16x8 __attribute__((ext_vector_type(8)));
typedef unsigned long long u64;

__device__ __forceinline__ float bf2f(unsigned short u) {
  union { unsigned int i; float f; } v; v.i = ((unsigned int)u) << 16; return v.f;
}
__device__ __forceinline__ unsigned short f2bf(float f) {
  union { float f; unsigned int u; } v; v.f = f;
  unsigned int r = v.u + 0x7fffu + ((v.u >> 16) & 1u);
  return (unsigned short)(r >> 16);
}
__device__ __forceinline__ float rcpf(float x) { return __builtin_amdgcn_rcpf(x); }
__device__ __forceinline__ u64 packft(float f, unsigned tag) {
  union { float f; unsigned u; } v; v.f = f;
  return ((u64)tag << 32) | (u64)v.u;
}
__device__ __forceinline__ float lo_f(u64 x) {
  union { unsigned u; float f; } v; v.u = (unsigned)x; return v.f;
}
__device__ __forceinline__ unsigned hi_u(u64 x) { return (unsigned)(x >> 32); }
__device__ __forceinline__ void postv(u64* p, u64 v) {
  __hip_atomic_store(p, v, __ATOMIC_RELAXED, __HIP_MEMORY_SCOPE_AGENT);
}
__device__ __forceinline__ u64 loadv(const u64* p) {
  return __hip_atomic_load(p, __ATOMIC_RELAXED, __HIP_MEMORY_SCOPE_AGENT);
}
__device__ __forceinline__ void postu(unsigned* p, unsigned v) {
  __hip_atomic_store(p, v, __ATOMIC_RELAXED, __HIP_MEMORY_SCOPE_AGENT);
}
__device__ __forceinline__ unsigned loadu(const unsigned* p) {
  return __hip_atomic_load(p, __ATOMIC_RELAXED, __HIP_MEMORY_SCOPE_AGENT);
}

// ---- decode tile: 128 rows (4t x 32b) x 128 cols, MFMA direct from memory ---
__device__ void decode_tile(int w, const unsigned* __restrict__ hallA,
                            const unsigned short* __restrict__ wdb,
                            float* __restrict__ out) {
  const int mt = w / NTN, nt = w - mt * NTN;
  const int m0 = mt * 128, n0 = nt * 128;
  const int tid = threadIdx.x;
  const int lane = tid & 63, wid = tid >> 6;
  const int wm = wid >> 2, wn = wid & 3;   // 2 x 4 wave grid
  const int lr = lane & 15, lk = lane >> 4;
  f32x4 acc[4][2];
  #pragma unroll
  for (int mi = 0; mi < 4; ++mi)
    #pragma unroll
    for (int ni = 0; ni < 2; ++ni) acc[mi][ni] = (f32x4)0.f;
  #pragma unroll
  for (int kc = 0; kc < 6; ++kc) {
    const int ku = kc * 16 + lk * 4;   // u32 index within hall row
    bf16x8 af[4], bf[2];
    #pragma unroll
    for (int mi = 0; mi < 4; ++mi) {
      int row = m0 + wm * 64 + mi * 16 + lr;
      const u64* p = (const u64*)(hallA + (size_t)row * HROW + ku);
      union { u64 q[2]; bf16x8 v; } u;
      u.q[0] = loadv(p); u.q[1] = loadv(p + 1);
      af[mi] = u.v;
    }
    #pragma unroll
    for (int ni = 0; ni < 2; ++ni) {
      int col = n0 + wn * 32 + ni * 16 + lr;
      bf[ni] = *(const bf16x8*)(wdb + (size_t)col * KP + kc * 32 + lk * 8);
    }
    #pragma unroll
    for (int mi = 0; mi < 4; ++mi)
      #pragma unroll
      for (int ni = 0; ni < 2; ++ni)
        acc[mi][ni] = __builtin_amdgcn_mfma_f32_16x16x32_bf16(
            af[mi], bf[ni], acc[mi][ni], 0, 0, 0);
  }
  #pragma unroll
  for (int mi = 0; mi < 4; ++mi)
    #pragma unroll
    for (int ni = 0; ni < 2; ++ni) {
      int col = n0 + wn * 32 + ni * 16 + lr;
      if (col < VV) {
        #pragma unroll
        for (int r = 0; r < 4; ++r) {
          int mrow = m0 + wm * 64 + mi * 16 + lk * 4 + r;
          int tt = mrow >> 5, bb2 = mrow & 31;
          out[((size_t)bb2 * TT + tt) * VV + col] = acc[mi][ni][r];
        }
      }
    }
}

__device__ __forceinline__ unsigned minprog(const unsigned* prog) {
  unsigned m = 1000000u;
  #pragma unroll 8
  for (int i = 0; i < BB; ++i) {
    unsigned v = loadu(&prog[i]);
    m = v < m ? v : m;
  }
  return m;
}

// ============ prep-all: Wdb (k-permuted), WihxT, WgT/WxS, zero Abuf/Pbuf/pw ==
#define NB_WDEC 4728   // NP2*KP/8/256
#define NB_TR   788    // ceil(ID*G4/256)
__global__ void k_prepall(const float* __restrict__ Wih, const float* __restrict__ Whh,
                          const float* __restrict__ attWx, const float* __restrict__ Wd,
                          float* __restrict__ WihxT, unsigned short* __restrict__ Wdb,
                          float* __restrict__ WgT, unsigned short* __restrict__ WxS,
                          u64* __restrict__ Abuf, u64* __restrict__ Pbuf,
                          unsigned* __restrict__ pw) {
  const int bid = blockIdx.x, tid = threadIdx.x;
  if (bid < NB_WDEC) {
    // Wdb[v][kp]: region rg = kp/24, off = kp%24; kreal = rg*21+off (off<21), else 0
    size_t e0 = ((size_t)bid * 256 + tid) * 8;
    int v = (int)(e0 / KP), kp0 = (int)(e0 - (size_t)v * KP);
    int rg = kp0 / 24, off0 = kp0 - rg * 24;   // off0 in {0,8,16}
    unsigned short o[8];
    if (v < VV) {
      const float* src = Wd + (size_t)v * HH + rg * RPB + off0;
      #pragma unroll
      for (int i = 0; i < 8; ++i) o[i] = (off0 + i < RPB) ? f2bf(src[i]) : 0;
    } else {
      #pragma unroll
      for (int i = 0; i < 8; ++i) o[i] = 0;
    }
    *(uint4*)(Wdb + e0) = *(const uint4*)o;
    return;
  }
  if (bid < NB_WDEC + NB_TR) {
    int idx = (bid - NB_WDEC) * 256 + tid;
    if (idx < ID * G4) {
      int k = idx / G4, i = idx - k * G4;
      WihxT[idx] = Wih[(size_t)i * IC + k];
    }
    return;
  }
  int idx = (bid - NB_WDEC - NB_TR) * 256 + tid;
  const int T1 = NJ * KK * WKP;             // 236544
  const int T2 = T1 + NJ * RPB * HH;        // +28224
  const int ZH = BB * NJ * LSLOT;           // 49152 u64 each
  const int T3 = T2 + 2 * ZH + 64;
  if (idx < T1) {
    int j = idx / (KK * WKP); int r = idx - j * (KK * WKP);
    int k = r / WKP, col = r - k * WKP;
    float w = 0.f;
    if (col < CPB) {
      int gt = col / RPB, rr = col - gt * RPB;
      int gcol = gt * HH + j * RPB + rr;
      w = (k < HH) ? Wih[(size_t)gcol * IC + ID + k] : Whh[(size_t)gcol * HH + (k - HH)];
    }
    WgT[idx] = w;
  } else if (idx < T2) {
    int r = idx - T1;
    WxS[r] = f2bf(attWx[r]);
  } else if (idx < T3) {
    int r = idx - T2;
    if (r < ZH) Abuf[r] = 0ull;
    else if (r < 2 * ZH) Pbuf[r - ZH] = 0ull;
    else pw[r - 2 * ZH] = 0u;
  }
}

// ============ seqproj (blocks 0..1023) + xproj (blocks 1024..1279) ===========
__global__ void k_seqxp(const float* __restrict__ ctx, const float* __restrict__ Ws,
                        const float* __restrict__ x, const float* __restrict__ WihxT,
                        const float* __restrict__ bih, const float* __restrict__ bhh,
                        unsigned short* __restrict__ ETs, unsigned short* __restrict__ ctxb,
                        float* __restrict__ Xp) {
  __shared__ float sbuf[2688];
  const int tid = threadIdx.x;
  if (blockIdx.x < 1024) {
    const int b = blockIdx.x & 31;
    const int s0 = (blockIdx.x >> 5) * 16;
    for (int idx = tid; idx < 16 * HH; idx += 256) {
      float v = ctx[(size_t)(b * SS + s0) * HH + idx];
      sbuf[idx] = v;
      ctxb[(size_t)(b * SS + s0) * HH + idx] = f2bf(v);
    }
    __syncthreads();
    #pragma unroll
    for (int o = 0; o < 11; ++o) {
      int idx = o * 256 + tid;
      if (idx < 16 * HH) {
        int s = idx / HH, h = idx - s * HH;
        const float* cr = &sbuf[s * HH];
        float acc = 0.f;
        #pragma unroll 4
        for (int c = 0; c < HH; ++c) acc = fmaf(cr[c], Ws[c * HH + h], acc);
        ETs[(size_t)(b * SS + s0 + s) * HH + h] = f2bf(__expf(2.f * acc));
      }
    }
  } else {
    const int r = blockIdx.x - 1024;
    const int t0 = (r & 7) * 8;
    const int b = r >> 3;
    for (int idx = tid; idx < 8 * ID; idx += 256)
      sbuf[idx] = x[(size_t)(b * TT + t0) * ID + idx];
    __syncthreads();
    for (int i = tid; i < G4; i += 256) {
      float bias = bih[i] + bhh[i];
      float acc[8];
      #pragma unroll
      for (int tt = 0; tt < 8; ++tt) acc[tt] = bias;
      for (int k = 0; k < ID; ++k) {
        float w = WihxT[k * G4 + i];
        #pragma unroll
        for (int tt = 0; tt < 8; ++tt) acc[tt] += sbuf[tt * ID + k] * w;
      }
      #pragma unroll
      for (int tt = 0; tt < 8; ++tt)
        Xp[(size_t)(b * TT + t0 + tt) * G4 + i] = acc[tt];
    }
  }
}

// ============ fused recurrence + work-stealing decode ========================
__global__ __launch_bounds__(512, 1) void k_recur(
    const int* __restrict__ lens, const float* __restrict__ attb,
    const float* __restrict__ attv, const float* __restrict__ WgT,
    const unsigned short* __restrict__ WxS, const unsigned short* __restrict__ ETs,
    const unsigned short* __restrict__ ctxb, const float* __restrict__ Xp,
    u64* __restrict__ Abuf, u64* __restrict__ Pbuf,
    unsigned* __restrict__ hallA, const unsigned short* __restrict__ Wdb,
    float* __restrict__ out, unsigned* __restrict__ pw) {
  const int b = blockIdx.x & 31;
  const int j = blockIdx.x >> 5;
  const int tid = threadIdx.x;
  unsigned* prog = pw;
  unsigned* wcnt = pw + 32;

  __shared__ float WgL[KK][WKP];            // 118272 B
  __shared__ unsigned short EL[SBLK][EPAD]; // 21760 B
  __shared__ unsigned short WxL[RPB][HH];   // 7056 B
  __shared__ float scratch[512];
  __shared__ float redH[504], redC[504];
  __shared__ float gE[HH], hsh[HH], abL[HH], vL[HH], attn[HH];
  __shared__ float esh[SBLK], hLoc[RPB], cLoc[RPB], wsum[8];
  __shared__ float sumv_s, bsum_s;
  __shared__ int sClaim;

  {
    const f32x4* src = (const f32x4*)(WgT + (size_t)j * KK * WKP);
    f32x4* dst = (f32x4*)WgL;
    for (int i = tid; i < KK * WKP / 4; i += 512) dst[i] = src[i];
  }
  for (int i = tid; i < SBLK * HH; i += 512) {
    int s = i / HH, h = i - s * HH;
    EL[s][h] = ETs[((size_t)b * SS + j * SBLK + s) * HH + h];
  }
  for (int i = tid; i < RPB * HH; i += 512)
    ((unsigned short*)WxL)[i] = WxS[(size_t)j * RPB * HH + i];
  if (tid < HH) { abL[tid] = attb[tid]; vL[tid] = attv[tid]; }
  if (tid < RPB) cLoc[tid] = 0.f;
  __syncthreads();
  if (tid == 0) {
    float s = 0.f;
    for (int h = 0; h < HH; ++h) s += vL[h];
    sumv_s = s;
  }
  const int len = lens[b];
  const int sbase = j * SBLK;
  u64* Amine = Abuf + (size_t)(b * NJ + j) * LSLOT;
  u64* Pmine = Pbuf + (size_t)(b * NJ + j) * LSLOT;
  __syncthreads();

  for (int t = 0; t < TT; ++t) {
    // ---- decode side-job: claim at most one ready tile (overlaps post RTT)
    if (tid == 0) {
      int w = -1;
      unsigned avail = minprog(prog);
      unsigned limit = (avail >= 4) ? (((avail - 4) >> 2) + 1) * (unsigned)NTN : 0u;
      if (limit > NTILES) limit = NTILES;
      if (limit) {
        unsigned cur = loadu(wcnt);
        if (cur < limit) {
          unsigned exp = cur;
          if (__hip_atomic_compare_exchange_strong(wcnt, &exp, cur + 1,
                __ATOMIC_RELAXED, __ATOMIC_RELAXED, __HIP_MEMORY_SCOPE_AGENT))
            w = (int)cur;
        }
      }
      sClaim = w;
    }
    __syncthreads();                                     // BAR 0
    if (sClaim >= 0) decode_tile(sClaim, hallA, Wdb, out);
    // ---- Xp prefetch (2 rows per thread, consumed in LSTM)
    float xa0=0,xa1=0,xa2=0,xa3=0, xb0=0,xb1=0,xb2=0,xb3=0;
    if (tid < 11) {
      const float* xp = Xp + ((size_t)b * TT + t) * G4 + j * RPB;
      int r0 = 2 * tid, r1 = r0 + 1;
      xa0 = xp[r0]; xa1 = xp[HH + r0]; xa2 = xp[2*HH + r0]; xa3 = xp[3*HH + r0];
      if (r1 < RPB) { xb0 = xp[r1]; xb1 = xp[HH + r1]; xb2 = xp[2*HH + r1]; xb3 = xp[3*HH + r1]; }
    }
    // ---- gE + hsh: poll tag-embedded a-partials (8) + h value (1)
    if (tid < HH) {
      float a = abL[tid], hv = 0.f;
      if (t > 0) {
        const unsigned want = (unsigned)t;
        const int jh = tid / RPB, hr = tid - jh * RPB;
        u64 va[9];
        int g = 0;
        for (;;) {
          #pragma unroll
          for (int jj = 0; jj < NJ; ++jj)
            va[jj] = loadv(&Abuf[(size_t)(b * NJ + jj) * LSLOT + tid]);
          va[8] = loadv(&Abuf[(size_t)(b * NJ + jh) * LSLOT + HH + hr]);
          bool ok = true;
          #pragma unroll
          for (int q = 0; q < 9; ++q) ok &= (hi_u(va[q]) >= want);
          if (ok) break;
          __builtin_amdgcn_s_sleep(1);
          if (++g > (1 << 24)) break;
        }
        #pragma unroll
        for (int jj = 0; jj < NJ; ++jj) a += lo_f(va[jj]);
        hv = lo_f(va[8]);
      }
      gE[tid] = __expf(2.f * a);
      hsh[tid] = hv;
    }
    __syncthreads();                                     // BAR A
    if (j == 0 && tid == 0 && t > 0) postu(&prog[b], (unsigned)t);
    // ---- B + softmax (wave-local)
    {
      int w = tid >> 6, lane = tid & 63;
      int sl = w * 8 + (lane >> 3);
      int hg = lane & 7;
      const unsigned short* er = &EL[sl][hg * RPB];
      const int hb = hg * RPB;
      float ep = 0.f;
      #pragma unroll 7
      for (int i = 0; i < RPB; ++i)
        ep += vL[hb + i] * rcpf(fmaf(gE[hb + i], bf2f(er[i]), 1.f));
      ep += __shfl_xor(ep, 1); ep += __shfl_xor(ep, 2); ep += __shfl_xor(ep, 4);
      float eh = (sbase + sl < len) ? __expf(sumv_s - 2.f * ep) : 0.f;
      float ws = (hg == 0) ? eh : 0.f;
      ws += __shfl_xor(ws, 8); ws += __shfl_xor(ws, 16); ws += __shfl_xor(ws, 32);
      if (lane == 0) wsum[w] = ws;
      if (hg == 0) esh[sl] = eh;
    }
    __syncthreads();                                     // BAR B
    // ---- C partials + bsum
    if (tid < 504) {
      int c = tid % HH, ch = tid / HH;
      const unsigned short* cb = ctxb + ((size_t)b * SS + sbase) * HH + c;
      float p = 0.f;
      for (int s = ch; s < SBLK; s += 3)
        p = fmaf(esh[s], bf2f(cb[(size_t)s * HH]), p);
      scratch[ch * HH + c] = p;
    } else if (tid == 504) {
      float bs = 0.f;
      #pragma unroll
      for (int w = 0; w < 8; ++w) bs += wsum[w];
      bsum_s = bs;
    }
    __syncthreads();                                     // BAR C
    // ---- post P (tag-embedded)
    if (tid < HH) {
      float p = scratch[tid] + scratch[HH + tid] + scratch[2 * HH + tid];
      postv(&Pmine[tid], packft(p, (unsigned)(t + 1)));
    } else if (tid == HH) {
      postv(&Pmine[HH], packft(bsum_s, (unsigned)(t + 1)));
    }
    // ---- D_h (overlaps P propagation)
    if (tid < 504) {
      int col = tid % CPB, kc = tid / CPB;
      int k0 = HH + kc * 28;
      float acc = 0.f;
      #pragma unroll 7
      for (int i = 0; i < 28; ++i)
        acc = fmaf(WgL[k0 + i][col], hsh[kc * 28 + i], acc);
      redH[kc * CPB + col] = acc;
    }
    // ---- attn finalize: poll p-lines directly
    if (tid < HH) {
      const unsigned want = (unsigned)(t + 1);
      u64 pv[NJ], bv[NJ];
      int g = 0;
      for (;;) {
        #pragma unroll
        for (int jj = 0; jj < NJ; ++jj) {
          const u64* pb = Pbuf + (size_t)(b * NJ + jj) * LSLOT;
          pv[jj] = loadv(&pb[tid]);
          bv[jj] = loadv(&pb[HH]);
        }
        bool ok = true;
        #pragma unroll
        for (int jj = 0; jj < NJ; ++jj) ok &= (hi_u(pv[jj]) >= want) & (hi_u(bv[jj]) >= want);
        if (ok) break;
        __builtin_amdgcn_s_sleep(1);
        if (++g > (1 << 24)) break;
      }
      float s = 0.f, den = 0.f;
      #pragma unroll
      for (int jj = 0; jj < NJ; ++jj) { s += lo_f(pv[jj]); den += lo_f(bv[jj]); }
      attn[tid] = s * rcpf(den);
    }
    __syncthreads();                                     // BAR D
    // ---- D_c
    if (tid < 504) {
      int col = tid % CPB, kc = tid / CPB;
      int k0 = kc * 28;
      float acc = 0.f;
      #pragma unroll 7
      for (int i = 0; i < 28; ++i)
        acc = fmaf(WgL[k0 + i][col], attn[k0 + i], acc);
      redC[kc * CPB + col] = acc;
    }
    __syncthreads();                                     // BAR E
    // ---- gates + LSTM: 11 threads x 2 rows; pack h pairs -> hallA u32 atomics
    if (tid < 12) {
      size_t hrow = ((size_t)t * BB + b) * HROW + j * 12;
      if (tid < 11) {
        const int r0 = 2 * tid, r1 = r0 + 1;
        float g0 = xa0, g1 = xa1, g2 = xa2, g3 = xa3;
        #pragma unroll
        for (int kc = 0; kc < 6; ++kc) {
          const float* rh = &redH[kc * CPB];
          const float* rc = &redC[kc * CPB];
          g0 += rh[r0] + rc[r0];
          g1 += rh[RPB + r0] + rc[RPB + r0];
          g2 += rh[2 * RPB + r0] + rc[2 * RPB + r0];
          g3 += rh[3 * RPB + r0] + rc[3 * RPB + r0];
        }
        float si = rcpf(1.f + __expf(-g0));
        float sf = rcpf(1.f + __expf(-g1));
        float tg = 1.f - 2.f * rcpf(1.f + __expf(2.f * g2));
        float so = rcpf(1.f + __expf(-g3));
        float cn = fmaf(sf, cLoc[r0], si * tg);
        float tc = 1.f - 2.f * rcpf(1.f + __expf(2.f * cn));
        float h0 = so * tc;
        cLoc[r0] = cn; hLoc[r0] = h0;
        unsigned hv = (unsigned)f2bf(h0);
        if (r1 < RPB) {
          float G0 = xb0, G1 = xb1, G2 = xb2, G3 = xb3;
          #pragma unroll
          for (int kc = 0; kc < 6; ++kc) {
            const float* rh = &redH[kc * CPB];
            const float* rc = &redC[kc * CPB];
            G0 += rh[r1] + rc[r1];
            G1 += rh[RPB + r1] + rc[RPB + r1];
            G2 += rh[2 * RPB + r1] + rc[2 * RPB + r1];
            G3 += rh[3 * RPB + r1] + rc[3 * RPB + r1];
          }
          float Si = rcpf(1.f + __expf(-G0));
          float Sf = rcpf(1.f + __expf(-G1));
          float Tg = 1.f - 2.f * rcpf(1.f + __expf(2.f * G2));
          float So = rcpf(1.f + __expf(-G3));
          float Cn = fmaf(Sf, cLoc[r1], Si * Tg);
          float Tc = 1.f - 2.f * rcpf(1.f + __expf(2.f * Cn));
          float h1 = So * Tc;
          cLoc[r1] = Cn; hLoc[r1] = h1;
          hv |= ((unsigned)f2bf(h1)) << 16;
        }
        postu(&hallA[hrow + tid], hv);
      } else {
        postu(&hallA[hrow + 11], 0u);
      }
    }
    __syncthreads();                                     // BAR F (drains hall stores)
    // ---- a_j = h_slice @ Wx_slice
    if (tid < 504) {
      int col = tid % HH, ch = tid / HH;
      float acc = 0.f;
      #pragma unroll
      for (int r = ch * 7; r < ch * 7 + 7; ++r)
        acc = fmaf(hLoc[r], bf2f(WxL[r][col]), acc);
      scratch[ch * HH + col] = acc;
    }
    __syncthreads();                                     // BAR G
    // ---- post a-partials + h values (tag-embedded)
    if (tid < HH) {
      float a = scratch[tid] + scratch[HH + tid] + scratch[2 * HH + tid];
      postv(&Amine[tid], packft(a, (unsigned)(t + 1)));
    } else if (tid < HH + RPB) {
      postv(&Amine[tid], packft(hLoc[tid - HH], (unsigned)(t + 1)));
    }
  }

  // ---- final progress: j0 confirms all blocks posted step TT
  if (j == 0) {
    if (tid < NJ) {
      int g = 0;
      while (hi_u(loadv(&Abuf[(size_t)(b * NJ + tid) * LSLOT])) < (unsigned)TT) {
        __builtin_amdgcn_s_sleep(2);
        if (++g > (1 << 24)) break;
      }
    }
    __syncthreads();
    if (tid == 0) postu(&prog[b], (unsigned)TT);
  }

  // ---- drain remaining decode tiles
  for (;;) {
    if (tid == 0) {
      int w = -1;
      for (int it = 0; it < (1 << 20); ++it) {
        unsigned cur = loadu(wcnt);
        if (cur >= NTILES) { w = -2; break; }
        unsigned avail = minprog(prog);
        unsigned limit = (avail >= 4) ? (((avail - 4) >> 2) + 1) * (unsigned)NTN : 0u;
        if (limit > NTILES) limit = NTILES;
        if (cur < limit) {
          unsigned exp = cur;
          if (__hip_atomic_compare_exchange_strong(wcnt, &exp, cur + 1,
                __ATOMIC_RELAXED, __ATOMIC_RELAXED, __HIP_MEMORY_SCOPE_AGENT)) {
            w = (int)cur; break;
          }
        } else {
          __builtin_amdgcn_s_sleep(8);
        }
      }
      sClaim = w;
    }
    __syncthreads();
    int w = sClaim;
    __syncthreads();
    if (w < 0) break;
    decode_tile(w, hallA, Wdb, out);
  }
}

extern "C" void kernel_launch(void* const* d_in, const int* in_sizes, int n_in,
                              void* d_out, int out_size, void* d_ws, size_t ws_size,
                              hipStream_t stream) {
  (void)in_sizes; (void)n_in; (void)out_size; (void)ws_size;
  const float* x     = (const float*)d_in[0];
  const float* ctx   = (const float*)d_in[1];
  const int*   lens  = (const int*)d_in[2];
  const float* Wih   = (const float*)d_in[3];
  const float* Whh   = (const float*)d_in[4];
  const float* bih   = (const float*)d_in[5];
  const float* bhh   = (const float*)d_in[6];
  const float* attWx = (const float*)d_in[7];
  const float* attWs = (const float*)d_in[8];
  const float* attb  = (const float*)d_in[9];
  const float* attv  = (const float*)d_in[10];
  const float* Wdec  = (const float*)d_in[11];
  float* out = (float*)d_out;

  char* base = (char*)d_ws;
  size_t off = 0;
  auto alloc = [&](size_t bytes) -> void* {
    off = (off + 255) & ~(size_t)255;
    void* p = base + off;
    off += bytes;
    return p;
  };
  unsigned short* ETs  = (unsigned short*)alloc((size_t)BB * SS * HH * 2);
  unsigned short* ctxb = (unsigned short*)alloc((size_t)BB * SS * HH * 2);
  float*          Xp   = (float*)alloc((size_t)BB * TT * G4 * 4);
  float*          WihxT= (float*)alloc((size_t)ID * G4 * 4);
  unsigned*       hallA= (unsigned*)alloc((size_t)BB * TT * HROW * 4);
  unsigned short* Wdb  = (unsigned short*)alloc((size_t)NP2 * KP * 2);
  float*          WgT  = (float*)alloc((size_t)NJ * KK * WKP * 4);
  unsigned short* WxS  = (unsigned short*)alloc((size_t)NJ * RPB * HH * 2);
  u64*            Abuf = (u64*)alloc((size_t)BB * NJ * LSLOT * 8);
  u64*            Pbuf = (u64*)alloc((size_t)BB * NJ * LSLOT * 8);
  unsigned*       pw   = (unsigned*)alloc(64 * 4);

  {
    const int TOTP = NJ * KK * WKP + NJ * RPB * HH + 2 * BB * NJ * LSLOT + 64;
    const int NBP = (TOTP + 255) / 256;
    k_prepall<<<dim3(NB_WDEC + NB_TR + NBP), dim3(256), 0, stream>>>(
        Wih, Whh, attWx, Wdec, WihxT, Wdb, WgT, WxS, Abuf, Pbuf, pw);
  }
  k_seqxp<<<dim3(1024 + 256), dim3(256), 0, stream>>>(ctx, attWs, x, WihxT,
                                                      bih, bhh, ETs, ctxb, Xp);
  {
    const int* a0 = lens; const float* a1 = attb; const float* a2 = attv;
    const float* a3 = WgT; const unsigned short* a4 = WxS;
    const unsigned short* a5 = ETs; const unsigned short* a6 = ctxb;
    const float* a7 = Xp; u64* a8 = Abuf; u64* a9 = Pbuf;
    unsigned* a10 = hallA; const unsigned short* a11 = Wdb;
    float* a12 = out; unsigned* a13 = pw;
    void* args[] = { &a0, &a1, &a2, &a3, &a4, &a5, &a6, &a7, &a8, &a9,
                     &a10, &a11, &a12, &a13 };
    hipLaunchCooperativeKernel((void*)k_recur, dim3(BB * NJ), dim3(512), args, 0, stream);
  }
}

// Round 8
// 834.223 us; speedup vs baseline: 18.2488x; 18.2488x over previous
//
#include <hip/hip_runtime.h>
#include <stdint.h>

#define BB 32
#define TT 64
#define ID 300
#define HH 168
#define SS 512
#define VV 50257
#define G4 672     // 4*H
#define IC 468     // I + C
#define KP 192     // K padded (8 regions x 24, k-permuted)
#define NP2 50432  // V padded to 256 (197 tiles)
#define NJ 8       // blocks per batch
#define RPB 21     // h rows per block
#define CPB 84     // gate cols per block
#define KK 336     // gate K dim
#define WKP 88     // WgT col pad
#define EPAD 170   // ETs LDS row pad
#define SBLK 64    // s positions per block
#define LSLOT 192  // u64 slots per (b,j) bucket
#define HROW 96    // u32 per hall row (KP/2)
#define LP 72      // decode LDS row pad in shorts
#define NTN 197    // decode n-tiles (50432/256)
#define NTILES 1576 // 8 m-tiles * 197

typedef float f32x4 __attribute__((ext_vector_type(4)));
typedef short bf16x8 __attribute__((ext_vector_type(8)));
typedef unsigned long long u64;

__device__ __forceinline__ float bf2f(unsigned short u) {
  union { unsigned int i; float f; } v; v.i = ((unsigned int)u) << 16; return v.f;
}
__device__ __forceinline__ unsigned short f2bf(float f) {
  union { float f; unsigned int u; } v; v.f = f;
  unsigned int r = v.u + 0x7fffu + ((v.u >> 16) & 1u);
  return (unsigned short)(r >> 16);
}
__device__ __forceinline__ float rcpf(float x) { return __builtin_amdgcn_rcpf(x); }
__device__ __forceinline__ u64 packft(float f, unsigned tag) {
  union { float f; unsigned u; } v; v.f = f;
  return ((u64)tag << 32) | (u64)v.u;
}
__device__ __forceinline__ float lo_f(u64 x) {
  union { unsigned u; float f; } v; v.u = (unsigned)x; return v.f;
}
__device__ __forceinline__ unsigned hi_u(u64 x) { return (unsigned)(x >> 32); }
__device__ __forceinline__ void postv(u64* p, u64 v) {
  __hip_atomic_store(p, v, __ATOMIC_RELAXED, __HIP_MEMORY_SCOPE_AGENT);
}
__device__ __forceinline__ u64 loadv(const u64* p) {
  return __hip_atomic_load(p, __ATOMIC_RELAXED, __HIP_MEMORY_SCOPE_AGENT);
}
__device__ __forceinline__ void postu(unsigned* p, unsigned v) {
  __hip_atomic_store(p, v, __ATOMIC_RELAXED, __HIP_MEMORY_SCOPE_AGENT);
}
__device__ __forceinline__ unsigned loadu(const unsigned* p) {
  return __hip_atomic_load(p, __ATOMIC_RELAXED, __HIP_MEMORY_SCOPE_AGENT);
}

// ============ prep-all: Wdb (k-permuted), WihxT, WgT/WxS, zero Abuf/Pbuf/pw ==
#define NB_WDEC 4728   // NP2*KP/8/256
#define NB_TR   788    // ceil(ID*G4/256)
__global__ void k_prepall(const float* __restrict__ Wih, const float* __restrict__ Whh,
                          const float* __restrict__ attWx, const float* __restrict__ Wd,
                          float* __restrict__ WihxT, unsigned short* __restrict__ Wdb,
                          float* __restrict__ WgT, unsigned short* __restrict__ WxS,
                          u64* __restrict__ Abuf, u64* __restrict__ Pbuf,
                          unsigned* __restrict__ pw) {
  const int bid = blockIdx.x, tid = threadIdx.x;
  if (bid < NB_WDEC) {
    // Wdb[v][kp]: region rg = kp/24, off = kp%24; kreal = rg*21+off (off<21), else 0
    size_t e0 = ((size_t)bid * 256 + tid) * 8;
    int v = (int)(e0 / KP), kp0 = (int)(e0 - (size_t)v * KP);
    int rg = kp0 / 24, off0 = kp0 - rg * 24;   // off0 in {0,8,16}
    unsigned short o[8];
    if (v < VV) {
      const float* src = Wd + (size_t)v * HH + rg * RPB + off0;
      #pragma unroll
      for (int i = 0; i < 8; ++i) o[i] = (off0 + i < RPB) ? f2bf(src[i]) : 0;
    } else {
      #pragma unroll
      for (int i = 0; i < 8; ++i) o[i] = 0;
    }
    *(uint4*)(Wdb + e0) = *(const uint4*)o;
    return;
  }
  if (bid < NB_WDEC + NB_TR) {
    int idx = (bid - NB_WDEC) * 256 + tid;
    if (idx < ID * G4) {
      int k = idx / G4, i = idx - k * G4;
      WihxT[idx] = Wih[(size_t)i * IC + k];
    }
    return;
  }
  int idx = (bid - NB_WDEC - NB_TR) * 256 + tid;
  const int T1 = NJ * KK * WKP;             // 236544
  const int T2 = T1 + NJ * RPB * HH;        // +28224
  const int ZH = BB * NJ * LSLOT;           // 49152 u64 each
  const int T3 = T2 + 2 * ZH + 64;
  if (idx < T1) {
    int j = idx / (KK * WKP); int r = idx - j * (KK * WKP);
    int k = r / WKP, col = r - k * WKP;
    float w = 0.f;
    if (col < CPB) {
      int gt = col / RPB, rr = col - gt * RPB;
      int gcol = gt * HH + j * RPB + rr;
      w = (k < HH) ? Wih[(size_t)gcol * IC + ID + k] : Whh[(size_t)gcol * HH + (k - HH)];
    }
    WgT[idx] = w;
  } else if (idx < T2) {
    int r = idx - T1;
    WxS[r] = f2bf(attWx[r]);
  } else if (idx < T3) {
    int r = idx - T2;
    if (r < ZH) Abuf[r] = 0ull;
    else if (r < 2 * ZH) Pbuf[r - ZH] = 0ull;
    else pw[r - 2 * ZH] = 0u;
  }
}

// ============ seqproj (blocks 0..1023) + xproj (blocks 1024..1279) ===========
__global__ void k_seqxp(const float* __restrict__ ctx, const float* __restrict__ Ws,
                        const float* __restrict__ x, const float* __restrict__ WihxT,
                        const float* __restrict__ bih, const float* __restrict__ bhh,
                        unsigned short* __restrict__ ETs, unsigned short* __restrict__ ctxb,
                        float* __restrict__ Xp) {
  __shared__ float sbuf[2688];
  const int tid = threadIdx.x;
  if (blockIdx.x < 1024) {
    const int b = blockIdx.x & 31;
    const int s0 = (blockIdx.x >> 5) * 16;
    for (int idx = tid; idx < 16 * HH; idx += 256) {
      float v = ctx[(size_t)(b * SS + s0) * HH + idx];
      sbuf[idx] = v;
      ctxb[(size_t)(b * SS + s0) * HH + idx] = f2bf(v);
    }
    __syncthreads();
    #pragma unroll
    for (int o = 0; o < 11; ++o) {
      int idx = o * 256 + tid;
      if (idx < 16 * HH) {
        int s = idx / HH, h = idx - s * HH;
        const float* cr = &sbuf[s * HH];
        float acc = 0.f;
        #pragma unroll 4
        for (int c = 0; c < HH; ++c) acc = fmaf(cr[c], Ws[c * HH + h], acc);
        ETs[(size_t)(b * SS + s0 + s) * HH + h] = f2bf(__expf(2.f * acc));
      }
    }
  } else {
    const int r = blockIdx.x - 1024;
    const int t0 = (r & 7) * 8;
    const int b = r >> 3;
    for (int idx = tid; idx < 8 * ID; idx += 256)
      sbuf[idx] = x[(size_t)(b * TT + t0) * ID + idx];
    __syncthreads();
    for (int i = tid; i < G4; i += 256) {
      float bias = bih[i] + bhh[i];
      float acc[8];
      #pragma unroll
      for (int tt = 0; tt < 8; ++tt) acc[tt] = bias;
      for (int k = 0; k < ID; ++k) {
        float w = WihxT[k * G4 + i];
        #pragma unroll
        for (int tt = 0; tt < 8; ++tt) acc[tt] += sbuf[tt * ID + k] * w;
      }
      #pragma unroll
      for (int tt = 0; tt < 8; ++tt)
        Xp[(size_t)(b * TT + t0 + tt) * G4 + i] = acc[tt];
    }
  }
}

// ============ fused recurrence (R6 structure) + tail decode ==================
__global__ __launch_bounds__(512, 1) void k_recur(
    const int* __restrict__ lens, const float* __restrict__ attb,
    const float* __restrict__ attv, const float* __restrict__ WgT,
    const unsigned short* __restrict__ WxS, const unsigned short* __restrict__ ETs,
    const unsigned short* __restrict__ ctxb, const float* __restrict__ Xp,
    u64* __restrict__ Abuf, u64* __restrict__ Pbuf,
    unsigned* __restrict__ hallA, const unsigned short* __restrict__ Wdb,
    float* __restrict__ out, unsigned* __restrict__ pw) {
  const int b = blockIdx.x & 31;
  const int j = blockIdx.x >> 5;
  const int tid = threadIdx.x;

  __shared__ __align__(16) float WgL[KK][WKP];  // 118272 B (reused as As/Bs in tail)
  __shared__ unsigned short EL[SBLK][EPAD];     // 21760 B
  __shared__ unsigned short WxL[RPB][HH];       // 7056 B
  __shared__ float scratch[512];
  __shared__ float redH[504], redC[504];
  __shared__ float gE[HH], hsh[HH], abL[HH], vL[HH], attn[HH];
  __shared__ float esh[SBLK], hLoc[RPB], cLoc[RPB], wsum[8];
  __shared__ float sumv_s, bsum_s;
  __shared__ int sClaim;

  {
    const f32x4* src = (const f32x4*)(WgT + (size_t)j * KK * WKP);
    f32x4* dst = (f32x4*)WgL;
    for (int i = tid; i < KK * WKP / 4; i += 512) dst[i] = src[i];
  }
  for (int i = tid; i < SBLK * HH; i += 512) {
    int s = i / HH, h = i - s * HH;
    EL[s][h] = ETs[((size_t)b * SS + j * SBLK + s) * HH + h];
  }
  for (int i = tid; i < RPB * HH; i += 512)
    ((unsigned short*)WxL)[i] = WxS[(size_t)j * RPB * HH + i];
  if (tid < HH) { abL[tid] = attb[tid]; vL[tid] = attv[tid]; }
  if (tid < RPB) cLoc[tid] = 0.f;
  __syncthreads();
  if (tid == 0) {
    float s = 0.f;
    for (int h = 0; h < HH; ++h) s += vL[h];
    sumv_s = s;
  }
  const int len = lens[b];
  const int sbase = j * SBLK;
  u64* Amine = Abuf + (size_t)(b * NJ + j) * LSLOT;
  u64* Pmine = Pbuf + (size_t)(b * NJ + j) * LSLOT;
  __syncthreads();

  for (int t = 0; t < TT; ++t) {
    // ---- Xp prefetch (2 rows/thread for the 11-thread LSTM)
    float xa0=0,xa1=0,xa2=0,xa3=0, xb0=0,xb1=0,xb2=0,xb3=0;
    if (tid < 11) {
      const float* xp = Xp + ((size_t)b * TT + t) * G4 + j * RPB;
      int r0 = 2 * tid, r1 = r0 + 1;
      xa0 = xp[r0]; xa1 = xp[HH + r0]; xa2 = xp[2*HH + r0]; xa3 = xp[3*HH + r0];
      if (r1 < RPB) { xb0 = xp[r1]; xb1 = xp[HH + r1]; xb2 = xp[2*HH + r1]; xb3 = xp[3*HH + r1]; }
    }
    // ---- gE + hsh: poll tag-embedded a-partials (8) + h value (1)
    if (tid < HH) {
      float a = abL[tid], hv = 0.f;
      if (t > 0) {
        const unsigned want = (unsigned)t;
        const int jh = tid / RPB, hr = tid - jh * RPB;
        u64 va[9];
        int g = 0;
        for (;;) {
          #pragma unroll
          for (int jj = 0; jj < NJ; ++jj)
            va[jj] = loadv(&Abuf[(size_t)(b * NJ + jj) * LSLOT + tid]);
          va[8] = loadv(&Abuf[(size_t)(b * NJ + jh) * LSLOT + HH + hr]);
          bool ok = true;
          #pragma unroll
          for (int q = 0; q < 9; ++q) ok &= (hi_u(va[q]) >= want);
          if (ok) break;
          __builtin_amdgcn_s_sleep(1);
          if (++g > (1 << 24)) break;
        }
        #pragma unroll
        for (int jj = 0; jj < NJ; ++jj) a += lo_f(va[jj]);
        hv = lo_f(va[8]);
      }
      gE[tid] = __expf(2.f * a);
      hsh[tid] = hv;
    }
    __syncthreads();                                     // BAR A
    // ---- B + softmax (wave-local)
    {
      int w = tid >> 6, lane = tid & 63;
      int sl = w * 8 + (lane >> 3);
      int hg = lane & 7;
      const unsigned short* er = &EL[sl][hg * RPB];
      const int hb = hg * RPB;
      float ep = 0.f;
      #pragma unroll 7
      for (int i = 0; i < RPB; ++i)
        ep += vL[hb + i] * rcpf(fmaf(gE[hb + i], bf2f(er[i]), 1.f));
      ep += __shfl_xor(ep, 1); ep += __shfl_xor(ep, 2); ep += __shfl_xor(ep, 4);
      float eh = (sbase + sl < len) ? __expf(sumv_s - 2.f * ep) : 0.f;
      float ws = (hg == 0) ? eh : 0.f;
      ws += __shfl_xor(ws, 8); ws += __shfl_xor(ws, 16); ws += __shfl_xor(ws, 32);
      if (lane == 0) wsum[w] = ws;
      if (hg == 0) esh[sl] = eh;
    }
    __syncthreads();                                     // BAR B
    // ---- C partials + bsum
    if (tid < 504) {
      int c = tid % HH, ch = tid / HH;
      const unsigned short* cb = ctxb + ((size_t)b * SS + sbase) * HH + c;
      float p = 0.f;
      for (int s = ch; s < SBLK; s += 3)
        p = fmaf(esh[s], bf2f(cb[(size_t)s * HH]), p);
      scratch[ch * HH + c] = p;
    } else if (tid == 504) {
      float bs = 0.f;
      #pragma unroll
      for (int w = 0; w < 8; ++w) bs += wsum[w];
      bsum_s = bs;
    }
    __syncthreads();                                     // BAR C
    // ---- post P (tag-embedded)
    if (tid < HH) {
      float p = scratch[tid] + scratch[HH + tid] + scratch[2 * HH + tid];
      postv(&Pmine[tid], packft(p, (unsigned)(t + 1)));
    } else if (tid == HH) {
      postv(&Pmine[HH], packft(bsum_s, (unsigned)(t + 1)));
    }
    // ---- D_h (overlaps P propagation)
    if (tid < 504) {
      int col = tid % CPB, kc = tid / CPB;
      int k0 = HH + kc * 28;
      float acc = 0.f;
      #pragma unroll 7
      for (int i = 0; i < 28; ++i)
        acc = fmaf(WgL[k0 + i][col], hsh[kc * 28 + i], acc);
      redH[kc * CPB + col] = acc;
    }
    // ---- attn finalize: poll p-lines directly
    if (tid < HH) {
      const unsigned want = (unsigned)(t + 1);
      u64 pv[NJ], bv[NJ];
      int g = 0;
      for (;;) {
        #pragma unroll
        for (int jj = 0; jj < NJ; ++jj) {
          const u64* pb = Pbuf + (size_t)(b * NJ + jj) * LSLOT;
          pv[jj] = loadv(&pb[tid]);
          bv[jj] = loadv(&pb[HH]);
        }
        bool ok = true;
        #pragma unroll
        for (int jj = 0; jj < NJ; ++jj) ok &= (hi_u(pv[jj]) >= want) & (hi_u(bv[jj]) >= want);
        if (ok) break;
        __builtin_amdgcn_s_sleep(1);
        if (++g > (1 << 24)) break;
      }
      float s = 0.f, den = 0.f;
      #pragma unroll
      for (int jj = 0; jj < NJ; ++jj) { s += lo_f(pv[jj]); den += lo_f(bv[jj]); }
      attn[tid] = s * rcpf(den);
    }
    __syncthreads();                                     // BAR D
    // ---- D_c
    if (tid < 504) {
      int col = tid % CPB, kc = tid / CPB;
      int k0 = kc * 28;
      float acc = 0.f;
      #pragma unroll 7
      for (int i = 0; i < 28; ++i)
        acc = fmaf(WgL[k0 + i][col], attn[k0 + i], acc);
      redC[kc * CPB + col] = acc;
    }
    __syncthreads();                                     // BAR E
    // ---- gates + LSTM: 11 threads x 2 rows; pack h pairs -> hallA u32 atomics
    if (tid < 12) {
      size_t hrow = ((size_t)b * TT + t) * HROW + j * 12;
      if (tid < 11) {
        const int r0 = 2 * tid, r1 = r0 + 1;
        float g0 = xa0, g1 = xa1, g2 = xa2, g3 = xa3;
        #pragma unroll
        for (int kc = 0; kc < 6; ++kc) {
          const float* rh = &redH[kc * CPB];
          const float* rc = &redC[kc * CPB];
          g0 += rh[r0] + rc[r0];
          g1 += rh[RPB + r0] + rc[RPB + r0];
          g2 += rh[2 * RPB + r0] + rc[2 * RPB + r0];
          g3 += rh[3 * RPB + r0] + rc[3 * RPB + r0];
        }
        float si = rcpf(1.f + __expf(-g0));
        float sf = rcpf(1.f + __expf(-g1));
        float tg = 1.f - 2.f * rcpf(1.f + __expf(2.f * g2));
        float so = rcpf(1.f + __expf(-g3));
        float cn = fmaf(sf, cLoc[r0], si * tg);
        float tc = 1.f - 2.f * rcpf(1.f + __expf(2.f * cn));
        float h0 = so * tc;
        cLoc[r0] = cn; hLoc[r0] = h0;
        unsigned hv = (unsigned)f2bf(h0);
        if (r1 < RPB) {
          float G0 = xb0, G1 = xb1, G2 = xb2, G3 = xb3;
          #pragma unroll
          for (int kc = 0; kc < 6; ++kc) {
            const float* rh = &redH[kc * CPB];
            const float* rc = &redC[kc * CPB];
            G0 += rh[r1] + rc[r1];
            G1 += rh[RPB + r1] + rc[RPB + r1];
            G2 += rh[2 * RPB + r1] + rc[2 * RPB + r1];
            G3 += rh[3 * RPB + r1] + rc[3 * RPB + r1];
          }
          float Si = rcpf(1.f + __expf(-G0));
          float Sf = rcpf(1.f + __expf(-G1));
          float Tg = 1.f - 2.f * rcpf(1.f + __expf(2.f * G2));
          float So = rcpf(1.f + __expf(-G3));
          float Cn = fmaf(Sf, cLoc[r1], Si * Tg);
          float Tc = 1.f - 2.f * rcpf(1.f + __expf(2.f * Cn));
          float h1 = So * Tc;
          cLoc[r1] = Cn; hLoc[r1] = h1;
          hv |= ((unsigned)f2bf(h1)) << 16;
        }
        postu(&hallA[hrow + tid], hv);
      } else {
        postu(&hallA[hrow + 11], 0u);
      }
    }
    __syncthreads();                                     // BAR F (drains hall stores)
    // ---- a = h_slice @ Wx_slice (168 thr x 21 FMA) + posts; no extra barrier
    if (tid < HH) {
      float acc = 0.f;
      #pragma unroll
      for (int r = 0; r < RPB; ++r)
        acc = fmaf(hLoc[r], bf2f(WxL[r][tid]), acc);
      postv(&Amine[tid], packft(acc, (unsigned)(t + 1)));
    } else if (tid < HH + RPB) {
      postv(&Amine[tid], packft(hLoc[tid - HH], (unsigned)(t + 1)));
    }
  }

  // ==== tail: all hall stores drained (BAR F each step); signal done =========
  __syncthreads();
  if (tid == 0) {
    __hip_atomic_fetch_add(&pw[0], 1u, __ATOMIC_RELAXED, __HIP_MEMORY_SCOPE_AGENT);
    int g = 0;
    while (loadu(&pw[0]) < (unsigned)(BB * NJ)) {
      __builtin_amdgcn_s_sleep(2);
      if (++g > (1 << 26)) break;
    }
  }
  __syncthreads();

  // ==== drain decode: 256x256 tiles, LDS overlaid on WgL, normal cached loads
  unsigned short* As = (unsigned short*)&WgL[0][0];
  unsigned short* Bs = As + 256 * LP;
  for (;;) {
    if (tid == 0) {
      unsigned w = __hip_atomic_fetch_add(&pw[32], 1u, __ATOMIC_RELAXED,
                                          __HIP_MEMORY_SCOPE_AGENT);
      sClaim = (w < NTILES) ? (int)w : -1;
    }
    __syncthreads();
    const int w = sClaim;
    if (w < 0) break;
    const int mt = w / NTN, nt = w - mt * NTN;
    const int m0 = mt * 256, n0 = nt * 256;
    const int lane = tid & 63, wid = tid >> 6;
    const int wm = wid >> 2, wn = wid & 3;
    const int lr = lane & 15, lk = lane >> 4;
    f32x4 acc[8][4];
    #pragma unroll
    for (int i = 0; i < 8; ++i)
      #pragma unroll
      for (int jj = 0; jj < 4; ++jj) acc[i][jj] = (f32x4)0.f;
    for (int k0 = 0; k0 < KP; k0 += 64) {
      if (k0) __syncthreads();
      #pragma unroll
      for (int i = 0; i < 4; ++i) {
        int flat = i * 512 + tid;
        int row = flat >> 3;
        int c8 = flat & 7;
        uint4 va = *(const uint4*)(hallA + (size_t)(m0 + row) * HROW + k0 / 2 + c8 * 4);
        *(uint4*)&As[row * LP + c8 * 8] = va;
        uint4 vb = *(const uint4*)(Wdb + (size_t)(n0 + row) * KP + k0 + c8 * 8);
        *(uint4*)&Bs[row * LP + c8 * 8] = vb;
      }
      __syncthreads();
      #pragma unroll
      for (int kk = 0; kk < 64; kk += 32) {
        bf16x8 af[8], bfr[4];
        #pragma unroll
        for (int mi = 0; mi < 8; ++mi)
          af[mi] = *(const bf16x8*)&As[(wm * 128 + mi * 16 + lr) * LP + kk + lk * 8];
        #pragma unroll
        for (int ni = 0; ni < 4; ++ni)
          bfr[ni] = *(const bf16x8*)&Bs[(wn * 64 + ni * 16 + lr) * LP + kk + lk * 8];
        #pragma unroll
        for (int mi = 0; mi < 8; ++mi)
          #pragma unroll
          for (int ni = 0; ni < 4; ++ni)
            acc[mi][ni] = __builtin_amdgcn_mfma_f32_16x16x32_bf16(
                af[mi], bfr[ni], acc[mi][ni], 0, 0, 0);
      }
    }
    #pragma unroll
    for (int mi = 0; mi < 8; ++mi)
      #pragma unroll
      for (int ni = 0; ni < 4; ++ni) {
        int col = n0 + wn * 64 + ni * 16 + lr;
        if (col < VV) {
          #pragma unroll
          for (int r = 0; r < 4; ++r) {
            int row = m0 + wm * 128 + mi * 16 + lk * 4 + r;
            out[(size_t)row * VV + col] = acc[mi][ni][r];
          }
        }
      }
    __syncthreads();  // all waves done with As/Bs before next claim restages
  }
}

extern "C" void kernel_launch(void* const* d_in, const int* in_sizes, int n_in,
                              void* d_out, int out_size, void* d_ws, size_t ws_size,
                              hipStream_t stream) {
  (void)in_sizes; (void)n_in; (void)out_size; (void)ws_size;
  const float* x     = (const float*)d_in[0];
  const float* ctx   = (const float*)d_in[1];
  const int*   lens  = (const int*)d_in[2];
  const float* Wih   = (const float*)d_in[3];
  const float* Whh   = (const float*)d_in[4];
  const float* bih   = (const float*)d_in[5];
  const float* bhh   = (const float*)d_in[6];
  const float* attWx = (const float*)d_in[7];
  const float* attWs = (const float*)d_in[8];
  const float* attb  = (const float*)d_in[9];
  const float* attv  = (const float*)d_in[10];
  const float* Wdec  = (const float*)d_in[11];
  float* out = (float*)d_out;

  char* base = (char*)d_ws;
  size_t off = 0;
  auto alloc = [&](size_t bytes) -> void* {
    off = (off + 255) & ~(size_t)255;
    void* p = base + off;
    off += bytes;
    return p;
  };
  unsigned short* ETs  = (unsigned short*)alloc((size_t)BB * SS * HH * 2);
  unsigned short* ctxb = (unsigned short*)alloc((size_t)BB * SS * HH * 2);
  float*          Xp   = (float*)alloc((size_t)BB * TT * G4 * 4);
  float*          WihxT= (float*)alloc((size_t)ID * G4 * 4);
  unsigned*       hallA= (unsigned*)alloc((size_t)BB * TT * HROW * 4);
  unsigned short* Wdb  = (unsigned short*)alloc((size_t)NP2 * KP * 2);
  float*          WgT  = (float*)alloc((size_t)NJ * KK * WKP * 4);
  unsigned short* WxS  = (unsigned short*)alloc((size_t)NJ * RPB * HH * 2);
  u64*            Abuf = (u64*)alloc((size_t)BB * NJ * LSLOT * 8);
  u64*            Pbuf = (u64*)alloc((size_t)BB * NJ * LSLOT * 8);
  unsigned*       pw   = (unsigned*)alloc(64 * 4);

  {
    const int TOTP = NJ * KK * WKP + NJ * RPB * HH + 2 * BB * NJ * LSLOT + 64;
    const int NBP = (TOTP + 255) / 256;
    k_prepall<<<dim3(NB_WDEC + NB_TR + NBP), dim3(256), 0, stream>>>(
        Wih, Whh, attWx, Wdec, WihxT, Wdb, WgT, WxS, Abuf, Pbuf, pw);
  }
  k_seqxp<<<dim3(1024 + 256), dim3(256), 0, stream>>>(ctx, attWs, x, WihxT,
                                                      bih, bhh, ETs, ctxb, Xp);
  {
    const int* a0 = lens; const float* a1 = attb; const float* a2 = attv;
    const float* a3 = WgT; const unsigned short* a4 = WxS;
    const unsigned short* a5 = ETs; const unsigned short* a6 = ctxb;
    const float* a7 = Xp; u64* a8 = Abuf; u64* a9 = Pbuf;
    unsigned* a10 = hallA; const unsigned short* a11 = Wdb;
    float* a12 = out; unsigned* a13 = pw;
    void* args[] = { &a0, &a1, &a2, &a3, &a4, &a5, &a6, &a7, &a8, &a9,
                     &a10, &a11, &a12, &a13 };
    hipLaunchCooperativeKernel((void*)k_recur, dim3(BB * NJ), dim3(512), args, 0, stream);
  }
}